// Round 15
// baseline (107.604 us; speedup 1.0000x reference)
//
#include <hip/hip_runtime.h>
#include <hip/hip_bf16.h>
#include <stdint.h>
#include <math.h>

#define H_HT 26
#define W_HT 122
#define NPIX (H_HT * W_HT)   // 3172
#define NA 60
#define NR 125
#define NB 32
#define NC 4
#define NBC (NB * NC)        // 128
#define PH 288
#define PW 800
#define NSPLIT 16            // rho splits per angle; wave bins r = q*4+w + 64t
#define PIX_PT 13            // ceil(3172/256) pixels per thread in csr
#define HBLKS (NA * NSPLIT)  // 960 hough blocks

#define TR_BLKS (H_HT * 8)               // 208 transpose blocks: (h, 16-bc group)
#define ZERO_BLKS 4

// ---- workspace layout (bytes) ----
#define WS_OFF   190336                    // int32 [60*126]          30240
#define WS_LIST  220608                    // uint16[60*3172]        380640
#define WS_PREDT 601280                    // float [3172*128]      1624064
#define WS_PVP   2225344                   // u64   [128*60]          61440
#define WS_CNT   2286784                   // u32 arrival counter

// ---------------- Kernel A: fused setup (unchanged, validated R14) ----------
__global__ __launch_bounds__(256) void setup(const float* __restrict__ pred,
                                             int* __restrict__ off,
                                             uint16_t* __restrict__ list,
                                             float* __restrict__ pred_T,
                                             unsigned long long* __restrict__ pvp,
                                             unsigned int* __restrict__ cnt) {
    const int tid = threadIdx.x;
    if (blockIdx.x < NA) {
        const int a = blockIdx.x;
        __shared__ int s_cnt[NR];
        __shared__ int sc[2][NR];
        __shared__ int s_pre[NR + 1];
        __shared__ int s_cur[NR];

        double t  = __dmul_rn((double)(a * 3), 0.017453292519943295);
        double cs = cos(t);
        double sn = sin(t);

        int rloc[PIX_PT];
#pragma unroll
        for (int k = 0; k < PIX_PT; ++k) {
            int p = tid + k * 256;
            rloc[k] = 0;
            if (p < NPIX) {
                int h = p / W_HT;
                int w = p - h * W_HT;
                double xs = (double)w - 60.5;
                double ys = (double)h - 12.5;
                double rho = __dadd_rn(__dmul_rn(xs, cs), __dmul_rn(ys, sn));
                int r = (int)rint(rho) + NR / 2;
                r = r < 0 ? 0 : (r > NR - 1 ? NR - 1 : r);
                rloc[k] = r;
            }
        }
        for (int i = tid; i < NR; i += 256) s_cnt[i] = 0;
        __syncthreads();
#pragma unroll
        for (int k = 0; k < PIX_PT; ++k) {
            int p = tid + k * 256;
            if (p < NPIX) atomicAdd(&s_cnt[rloc[k]], 1);
        }
        __syncthreads();
        if (tid < NR) sc[0][tid] = s_cnt[tid];
        __syncthreads();
        int pin = 0;
        for (int d = 1; d < NR; d <<= 1) {
            if (tid < NR) {
                int v = sc[pin][tid];
                if (tid >= d) v += sc[pin][tid - d];
                sc[pin ^ 1][tid] = v;
            }
            __syncthreads();
            pin ^= 1;
        }
        if (tid == 0) s_pre[0] = 0;
        if (tid < NR) s_pre[tid + 1] = sc[pin][tid];
        __syncthreads();
        for (int r = tid; r < NR + 1; r += 256) off[a * (NR + 1) + r] = s_pre[r];
        for (int r = tid; r < NR; r += 256) s_cur[r] = s_pre[r];
        __syncthreads();
#pragma unroll
        for (int k = 0; k < PIX_PT; ++k) {
            int p = tid + k * 256;
            if (p < NPIX) {
                int slot = atomicAdd(&s_cur[rloc[k]], 1);
                list[a * NPIX + slot] = (uint16_t)p;
            }
        }
    } else if (blockIdx.x < NA + TR_BLKS) {
        const int bidx = blockIdx.x - NA;
        const int h    = bidx >> 3;        // 0..25
        const int g    = bidx & 7;         // 0..7
        const int bc0  = g * 16;
        __shared__ float s_row[16][802];
        const float C1 = (float)(288.0 / 26.0);
        const float C2 = (float)(800.0 / 122.0);
        const int hi = (int)floorf((float)h * C1);
        for (int i = tid; i < 16 * 200; i += 256) {
            int j  = i / 200;
            int c4 = i - j * 200;
            const float4* rp = reinterpret_cast<const float4*>(
                pred + ((size_t)(bc0 + j) * PH + hi) * PW);
            float4 v = rp[c4];
            s_row[j][c4 * 4 + 0] = v.x;
            s_row[j][c4 * 4 + 1] = v.y;
            s_row[j][c4 * 4 + 2] = v.z;
            s_row[j][c4 * 4 + 3] = v.w;
        }
        __syncthreads();
        for (int idx = tid; idx < W_HT * 16; idx += 256) {
            int w = idx >> 4;              // 0..121
            int j = idx & 15;
            int wi = (int)floorf((float)w * C2);
            pred_T[(size_t)(h * W_HT + w) * NBC + bc0 + j] = s_row[j][wi];
        }
    } else {
        int bz = blockIdx.x - NA - TR_BLKS;
        int i0 = bz * 256 + tid;
        for (int i = i0; i < NA * NBC; i += ZERO_BLKS * 256) pvp[i] = 0ull;
        if (bz == 0 && tid == 0) *cnt = 0u;
    }
}

// ---------------- Kernel B: hough (16-deep ILP) + last-arriver fused loss ---
__global__ __launch_bounds__(256) void hough_loss(const float* __restrict__ pred_T,
                                                  const int* __restrict__ off,
                                                  const uint16_t* __restrict__ list,
                                                  unsigned long long* __restrict__ pvp,
                                                  unsigned int* __restrict__ cnt,
                                                  const float* __restrict__ ht,
                                                  const float* __restrict__ pexist,
                                                  float* __restrict__ out) {
    __shared__ uint16_t s_list[NPIX];    // 6344 B
    __shared__ int      s_off[NR + 1];
    __shared__ float    s_v0[4][64], s_v1[4][64];
    __shared__ int      s_i0[4][64], s_i1[4][64];

    const int blk  = blockIdx.x;
    const int a    = blk / NSPLIT;
    const int q    = blk - a * NSPLIT;
    const int tid  = threadIdx.x;
    const int w    = tid >> 6;
    const int lane = tid & 63;

    {   // stage full angle list (coalesced as uint32) + offsets
        const uint32_t* src = reinterpret_cast<const uint32_t*>(list + a * NPIX);
        uint32_t* dst = reinterpret_cast<uint32_t*>(s_list);
        for (int i = tid; i < NPIX / 2; i += 256) dst[i] = src[i];
        for (int r = tid; r < NR + 1; r += 256) s_off[r] = off[a * (NR + 1) + r];
    }
    __syncthreads();

    const float2* pT2 = reinterpret_cast<const float2*>(pred_T);
    float bv0 = -1.0f, bv1 = -1.0f; int bi0 = 0x7fffffff, bi1 = 0x7fffffff;
    for (int r = q * 4 + w; r < NR; r += 64) {
        int o0 = s_off[r];
        int o1 = s_off[r + 1];
        float ax[8] = {0,0,0,0,0,0,0,0}, ay[8] = {0,0,0,0,0,0,0,0};
        int j = o0;
        for (; j + 16 <= o1; j += 16) {
            float2 v[16];
#pragma unroll
            for (int k = 0; k < 16; ++k)
                v[k] = pT2[(int)s_list[j + k] * 64 + lane];
#pragma unroll
            for (int k = 0; k < 16; ++k) { ax[k & 7] += v[k].x; ay[k & 7] += v[k].y; }
        }
        for (; j < o1; ++j) {
            float2 vv = pT2[(int)s_list[j] * 64 + lane];
            ax[0] += vv.x; ay[0] += vv.y;
        }
        float sx = ((ax[0] + ax[1]) + (ax[2] + ax[3])) + ((ax[4] + ax[5]) + (ax[6] + ax[7]));
        float sy = ((ay[0] + ay[1]) + (ay[2] + ay[3])) + ((ay[4] + ay[5]) + (ay[6] + ay[7]));
        int gbin = a * NR + r;
        if (sx > bv0) { bv0 = sx; bi0 = gbin; }
        if (sy > bv1) { bv1 = sy; bi1 = gbin; }
    }
    s_v0[w][lane] = bv0; s_i0[w][lane] = bi0;
    s_v1[w][lane] = bv1; s_i1[w][lane] = bi1;
    __syncthreads();
    if (w == 0) {
        float m0 = s_v0[0][lane], m1 = s_v1[0][lane];
        int   j0 = s_i0[0][lane], j1 = s_i1[0][lane];
#pragma unroll
        for (int ww = 1; ww < 4; ++ww) {
            float o0v = s_v0[ww][lane]; int o0i = s_i0[ww][lane];
            float o1v = s_v1[ww][lane]; int o1i = s_i1[ww][lane];
            if (o0v > m0 || (o0v == m0 && o0i < j0)) { m0 = o0v; j0 = o0i; }
            if (o1v > m1 || (o1v == m1 && o1i < j1)) { m1 = o1v; j1 = o1i; }
        }
        unsigned long long e0 = ((unsigned long long)__float_as_uint(m0 < 0.f ? 0.f : m0) << 32)
                              | (unsigned long long)(65535 - j0);
        unsigned long long e1 = ((unsigned long long)__float_as_uint(m1 < 0.f ? 0.f : m1) << 32)
                              | (unsigned long long)(65535 - j1);
        atomicMax(&pvp[(2 * lane)     * NA + a], e0);
        atomicMax(&pvp[(2 * lane + 1) * NA + a], e1);
    }

    // ---- last-arriver loss tail (no block ever waits; deadlock-free) ----
    __shared__ unsigned int s_last;
    __threadfence();
    __syncthreads();
    if (tid == 0) s_last = atomicAdd(cnt, 1u);
    __syncthreads();
    if (s_last != (unsigned int)(HBLKS - 1)) return;
    __threadfence();   // acquire: see all pvp atomicMax results

    __shared__ int   s_fidx[NBC];
    __shared__ float s_t1[256], s_t2[256];

    if (tid < NBC) {   // per (b,k): argmax over 60 angles
        unsigned long long be = 0ull;
        const unsigned long long* pr = pvp + tid * NA;
        for (int aa = 0; aa < NA; ++aa) {
            unsigned long long e = pr[aa];
            if (e > be) be = e;
        }
        s_fidx[tid] = 65535 - (int)(be & 0xFFFFull);
    }
    __syncthreads();

#pragma unroll
    for (int it = 0; it < 2; ++it) {
        int T = tid + 256 * it;           // task 0..511 = (b, c, k)
        int b = T >> 4;
        int combo = T & 15;
        int c = combo >> 2;
        int k = combo & 3;
        int fidx = s_fidx[b * 4 + k];
        int a0 = fidx / NR;
        int r  = fidx - a0 * NR;
        const float* htc = ht + (size_t)((b * 4 + c) * NA) * NR;
        float acc = 0.0f;
        for (int aa = 0; aa < NA; ++aa) acc += fabsf(htc[aa * NR + r]);
        float l1 = fmaxf(acc, 1e-12f);
        float gg = htc[a0 * NR + r] / l1;
        float ex = (pexist[b * 4 + k] > 0.9f) ? 1.0f : 0.0f;
        float term = -logf(gg + 1e-12f) * ex;
        if (it == 0) s_t1[tid] = term; else s_t2[tid] = term;
    }
    __syncthreads();
    if (tid < 32) {    // deterministic per-b tree: sum 16 terms serially
        int b = tid;
        float s = 0.0f;
        if (b < 16) { for (int i = 0; i < 16; ++i) s += s_t1[b * 16 + i]; }
        else        { for (int i = 0; i < 16; ++i) s += s_t2[(b - 16) * 16 + i]; }
        out[b] = s * (1.0f / 16.0f);
    }
}

extern "C" void kernel_launch(void* const* d_in, const int* in_sizes, int n_in,
                              void* d_out, int out_size, void* d_ws, size_t ws_size,
                              hipStream_t stream) {
    const float* ht     = (const float*)d_in[0];
    const float* pred   = (const float*)d_in[1];
    const float* pexist = (const float*)d_in[2];

    char* ws = (char*)d_ws;
    int*      off    = (int*)     (ws + WS_OFF);
    uint16_t* list   = (uint16_t*)(ws + WS_LIST);
    float*    pred_T = (float*)   (ws + WS_PREDT);
    unsigned long long* pvp = (unsigned long long*)(ws + WS_PVP);
    unsigned int* cnt = (unsigned int*)(ws + WS_CNT);

    setup<<<NA + TR_BLKS + ZERO_BLKS, 256, 0, stream>>>(pred, off, list, pred_T, pvp, cnt);
    hough_loss<<<HBLKS, 256, 0, stream>>>(pred_T, off, list, pvp, cnt, ht, pexist, (float*)d_out);
}